// Round 1
// baseline (100.825 us; speedup 1.0000x reference)
//
#include <hip/hip_runtime.h>
#include <stdint.h>

#define NROWS 8192
#define KDIM  512                           // k elems (= bytes in fp8) per row
#define BM    128
#define BK    128                           // k-bytes per stage
#define NKI   (KDIM / BK)                   // 4 K-iters
#define NT    (NROWS / BM)                  // 64 tiles per dim
#define NBLK  (NT * (NT + 1) / 2)           // 2080 upper-tri blocks

typedef __attribute__((ext_vector_type(4)))  int   i32x4;
typedef __attribute__((ext_vector_type(8)))  int   i32x8;
typedef __attribute__((ext_vector_type(16))) float f32x16;

__device__ __forceinline__ void async_copy16(const unsigned char* g, unsigned char* l) {
  __builtin_amdgcn_global_load_lds(
      (const __attribute__((address_space(1))) unsigned int*)g,
      (__attribute__((address_space(3))) unsigned int*)l,
      16, 0, 0);
}

// Kernel 1: row-normalize fp32 -> fp8 e4m3 (RNE), one wave per row (no LDS,
// no barriers). PRE-SWIZZLED layout for BK=128 staging windows:
//   within each 128B window, 16B chunk c sits at position c ^ (row & 7)
// R12 change (MX-MFMA): the 8B half-swap (old swizzle (b)) is DROPPED.
// 32x32x64 fragments are read as whole adjacent 16B chunks via ds_read_b128,
// so halves must stay in natural order inside each chunk; chunk-XOR alone
// gives 8 distinct 16B slots per 16-lane read phase -> 2-way bank aliasing,
// which is free (m136).
__global__ __launch_bounds__(256) void prep_kernel(
    const float* __restrict__ src, unsigned char* __restrict__ dst,
    float* __restrict__ acc) {
  const int row  = blockIdx.x * 4 + (threadIdx.x >> 6);
  const int lane = threadIdx.x & 63;
  const float4 v0 = ((const float4*)src)[row * 128 + lane * 2];
  const float4 v1 = ((const float4*)src)[row * 128 + lane * 2 + 1];
  float ss = v0.x * v0.x + v0.y * v0.y + v0.z * v0.z + v0.w * v0.w
           + v1.x * v1.x + v1.y * v1.y + v1.z * v1.z + v1.w * v1.w;
  #pragma unroll
  for (int off = 32; off > 0; off >>= 1) ss += __shfl_down(ss, off);
  const float rn = 1.0f / sqrtf(__shfl(ss, 0));   // norms ~22.6, EPS never fires
  if (row == 0 && lane == 0) *acc = 0.0f;
  int pk0 = __builtin_amdgcn_cvt_pk_fp8_f32(v0.x * rn, v0.y * rn, 0, false);
  pk0     = __builtin_amdgcn_cvt_pk_fp8_f32(v0.z * rn, v0.w * rn, pk0, true);
  int pk1 = __builtin_amdgcn_cvt_pk_fp8_f32(v1.x * rn, v1.y * rn, 0, false);
  pk1     = __builtin_amdgcn_cvt_pk_fp8_f32(v1.z * rn, v1.w * rn, pk1, true);
  // lane's 8 logical bytes = 16B chunk cg = lane>>1, half = lane&1.
  const int cg  = lane >> 1;
  const int win = cg >> 3;                          // 128B window (0..3)
  const int p   = (cg & 7) ^ (row & 7);             // chunk swizzle
  const int hf  = lane & 1;                         // natural half order (R12)
  uint2 o; o.x = (unsigned int)pk0; o.y = (unsigned int)pk1;
  ((uint2*)dst)[row * 64 + win * 16 + p * 2 + hf] = o;   // win*16: R11 fix
}

__device__ __forceinline__ int tri_base(int b) {   // # tiles before row b
  return b * NT - (b * (b - 1)) / 2;
}

// Kernel 2: fp8 MFMA GEMM (idn @ idn^T) fused with clamp, diagonal masking,
// full reduction.
// R12: switched 16x16x32 non-scaled fp8 (bf16-rate, ~2.1 PF) -> MX-scaled
// 32x32x64 f8f6f4 with E8M0 scale 127 (=1.0): numerically identical e4m3
// products, fp32 accum, at the ~4.7 PF scaled rate (m21/m59/m148). MFMA
// floor 16.8us -> ~7.8us; instruction count 1024 -> 128 per block. The
// kernel becomes L2->LDS transfer-bound (~17us component, R9), which the
// vmcnt(8) 2-stage pipeline already overlaps.
// Per-lane A/B operand: row=lane&31, k=(lane>>5)*32+j (generalization of the
// verified 16x16x32 mapping); 32B/lane = two adjacent 16B chunks read as
// 2x ds_read_b128 at swizzled slots (c0^rx, (c0+1)^rx).
// 1D triangular grid -- whole 4MB fp8 matrix is L2-resident per XCD.
// Strictly-upper tiles weighted 2x by symmetry.
__global__ __launch_bounds__(256) void sim_reduce_kernel(
    const unsigned char* __restrict__ idn, float* __restrict__ acc) {
  // triangular decode (block-uniform scalar math, R1-proven)
  const int idx = blockIdx.x;
  const float Af = 2.0f * NT + 1.0f;
  int bi = (int)((Af - sqrtf(Af * Af - 8.0f * (float)idx)) * 0.5f);
  while (bi > 0 && tri_base(bi) > idx) bi--;
  while (tri_base(bi + 1) <= idx) bi++;
  const int bj = bi + (idx - tri_base(bi));

  __shared__ __align__(16) unsigned char As[2][BM * BK];   // 2 x 16 KB
  __shared__ __align__(16) unsigned char Bs[2][BM * BK];   // 2 x 16 KB

  const int tid  = threadIdx.x;      // 0..255, 4 waves
  const int lane = tid & 63;
  const int w    = tid >> 6;
  const int wr   = (w >> 1) * 64;    // wave's 64x64 quadrant
  const int wc   = (w & 1) * 64;
  const int r32  = lane & 31;        // row within 32-row MFMA tile
  const int h    = lane >> 5;        // k-half selector (k = h*32 + j)
  const int rx   = r32 & 7;          // chunk swizzle key

  f32x16 acc_f[2][2];
  #pragma unroll
  for (int i = 0; i < 2; i++)
    #pragma unroll
    for (int j = 0; j < 2; j++)
      acc_f[i][j] = (f32x16){0.f, 0.f, 0.f, 0.f, 0.f, 0.f, 0.f, 0.f,
                             0.f, 0.f, 0.f, 0.f, 0.f, 0.f, 0.f, 0.f};

  // Staging: per stage, 1024 chunks of 16B; thread t covers chunks t+i*256
  // (i=0..3): row (t>>3)+i*32, in-window slot t&7. 8 lanes cover one row's
  // 128B window contiguously -> coalesced. Memory already holds the
  // swizzled chunk order; LDS dest lane-linear (t*16).
  const unsigned char* gA = idn + (size_t)(bi * BM + (tid >> 3)) * KDIM + (tid & 7) * 16;
  const unsigned char* gB = idn + (size_t)(bj * BM + (tid >> 3)) * KDIM + (tid & 7) * 16;
  const int ldso = tid * 16;         // + i*4096 per chunk group

  // prologue: stage 0 <- k-window 0
  #pragma unroll
  for (int i = 0; i < 4; i++) async_copy16(gA + (size_t)i * 16384, &As[0][ldso + i * 4096]);
  #pragma unroll
  for (int i = 0; i < 4; i++) async_copy16(gB + (size_t)i * 16384, &Bs[0][ldso + i * 4096]);

  #pragma unroll
  for (int t = 0; t < NKI; ++t) {
    const int cs = t & 1;
    if (t + 1 < NKI) {
      const int ns = cs ^ 1;
      const int ko = (t + 1) * BK;
      #pragma unroll
      for (int i = 0; i < 4; i++)
        async_copy16(gA + ko + (size_t)i * 16384, &As[ns][ldso + i * 4096]);
      #pragma unroll
      for (int i = 0; i < 4; i++)
        async_copy16(gB + ko + (size_t)i * 16384, &Bs[ns][ldso + i * 4096]);
      asm volatile("s_waitcnt vmcnt(8)" ::: "memory");  // stage t landed; t+1 in flight
    } else {
      asm volatile("s_waitcnt vmcnt(0)" ::: "memory");
    }
    asm volatile("s_barrier" ::: "memory");   // all waves' stage-t fills visible

    // 2 k-slices (K=64 each) per BK=128 stage. Lane (r32,h), slice ks:
    // logical chunks c0=4ks+2h and c0+1 at swizzled slots ^rx. Each frag =
    // 2x ds_read_b128; per 16-lane phase 8 distinct slots -> 2-way (free).
    #pragma unroll
    for (int ks = 0; ks < 2; ks++) {
      const int c0 = 4 * ks + 2 * h;
      const int p0 = ((c0)     ^ rx) * 16;
      const int p1 = ((c0 + 1) ^ rx) * 16;
      i32x8 af[2], bf[2];
      #pragma unroll
      for (int mi = 0; mi < 2; mi++) {
        const unsigned char* ab = &As[cs][(wr + mi * 32 + r32) * BK];
        const i32x4 alo = *(const i32x4*)(ab + p0);
        const i32x4 ahi = *(const i32x4*)(ab + p1);
        af[mi] = __builtin_shufflevector(alo, ahi, 0, 1, 2, 3, 4, 5, 6, 7);
        const unsigned char* bb = &Bs[cs][(wc + mi * 32 + r32) * BK];
        const i32x4 blo = *(const i32x4*)(bb + p0);
        const i32x4 bhi = *(const i32x4*)(bb + p1);
        bf[mi] = __builtin_shufflevector(blo, bhi, 0, 1, 2, 3, 4, 5, 6, 7);
      }
      #pragma unroll
      for (int mi = 0; mi < 2; mi++)
        #pragma unroll
        for (int ni = 0; ni < 2; ni++)
          acc_f[mi][ni] = __builtin_amdgcn_mfma_scale_f32_32x32x64_f8f6f4(
              af[mi], bf[ni], acc_f[mi][ni],
              0, 0,                       // A fmt = fp8 e4m3, B fmt = fp8 e4m3
              0, 0x7F7F7F7Fu,             // A scale: E8M0 127 -> 1.0
              0, 0x7F7F7F7Fu);            // B scale: E8M0 127 -> 1.0
    }

    asm volatile("s_barrier" ::: "memory");   // compute(t) done before t+1 refill
  }

  // Epilogue: clamp at zero, mask diagonal, reduce.
  // C/D layout for 32x32 shapes (m74/m101; dtype-independent m121-m128):
  // col = lane&31, row = (reg&3) + 8*(reg>>2) + 4*(lane>>5).
  float local = 0.f;
  const bool diag = (bi == bj);
  #pragma unroll
  for (int mi = 0; mi < 2; mi++)
    #pragma unroll
    for (int ni = 0; ni < 2; ni++)
      #pragma unroll
      for (int rg = 0; rg < 16; rg++) {
        const int ri = wr + mi * 32 + (rg & 3) + 8 * (rg >> 2) + 4 * h;
        const int ci = wc + ni * 32 + r32;
        float v = fmaxf(acc_f[mi][ni][rg], 0.f);
        if (diag && ri == ci) v = 0.f;
        local += v;
      }

  #pragma unroll
  for (int off = 32; off > 0; off >>= 1) local += __shfl_down(local, off);
  __syncthreads();                   // staging dead; reuse As for reduce
  float* red = (float*)As;
  if (lane == 0) red[w] = local;
  __syncthreads();
  if (tid == 0) {
    float s = red[0] + red[1] + red[2] + red[3];
    if (!diag) s *= 2.f;             // strictly-upper tiles cover both triangles
    atomicAdd(acc, s);
  }
}

// Kernel 3: scale and write both outputs (total_loss == l_id_div, DIV_COEF=1).
__global__ void finalize_kernel(const float* __restrict__ acc, float* __restrict__ out) {
  const float m = *acc * (1.0f / ((float)NROWS * (float)NROWS));
  out[0] = m;
  out[1] = m;
}

extern "C" void kernel_launch(void* const* d_in, const int* in_sizes, int n_in,
                              void* d_out, int out_size, void* d_ws, size_t ws_size,
                              hipStream_t stream) {
  const float* id = (const float*)d_in[0];
  float* out = (float*)d_out;
  unsigned char* idn = (unsigned char*)d_ws;                       // 4 MB fp8
  float* acc = (float*)((char*)d_ws + (size_t)NROWS * KDIM);

  prep_kernel<<<NROWS / 4, 256, 0, stream>>>(id, idn, acc);
  sim_reduce_kernel<<<NBLK, 256, 0, stream>>>(idn, acc);
  finalize_kernel<<<1, 1, 0, stream>>>(acc, out);
}

// Round 2
// 96.341 us; speedup vs baseline: 1.0465x; 1.0465x over previous
//
#include <hip/hip_runtime.h>
#include <stdint.h>

#define NROWS 8192
#define KDIM  512                           // k elems (= bytes in fp8) per row
#define BM    256                           // R13: 256x256 tiles (was 128)
#define BK    64                            // k-bytes per stage (was 128)
#define NKI   (KDIM / BK)                   // 8 K-iters
#define NT    (NROWS / BM)                  // 32 tiles per dim
#define NBLK  (NT * (NT + 1) / 2)           // 528 upper-tri blocks

typedef __attribute__((ext_vector_type(4)))  int   i32x4;
typedef __attribute__((ext_vector_type(8)))  int   i32x8;
typedef __attribute__((ext_vector_type(16))) float f32x16;

__device__ __forceinline__ void async_copy16(const unsigned char* g, unsigned char* l) {
  __builtin_amdgcn_global_load_lds(
      (const __attribute__((address_space(1))) unsigned int*)g,
      (__attribute__((address_space(3))) unsigned int*)l,
      16, 0, 0);
}

// Kernel 1: row-normalize fp32 -> fp8 e4m3 (RNE), one wave per row.
// R13 PRE-SWIZZLE for BK=64 staging windows: the row is 8 windows of 64B
// (4 chunks of 16B). Within window, logical chunk c stored at physical slot
//   p = c ^ ((row>>1) & 3)
// Bank math (64B LDS row stride): bank = (row*16 + p*4 + word) & 31 -- only
// row bit 0 + slot + word select the bank. Per 16-lane ds_read_b128 phase
// (16 consecutive rows, fixed logical c): 2 parities x 4 slots x 4 words =
// 32 banks, each row-parity's 8 rows land on 4 slots twice -> 2-way
// aliasing, which is free (m136). Halves inside each 16B chunk stay in
// natural order (fragments are whole-chunk ds_read_b128, verified R12).
// Worked example: row 5 (key=2), chunk cg=6 -> window 1, c=2, slot 0;
// sim reads h=1 frag (chunks 2,3) at p0=2^2=0 ✓, p1=3^2=1 -> c=1^2... =3 ✓.
__global__ __launch_bounds__(256) void prep_kernel(
    const float* __restrict__ src, unsigned char* __restrict__ dst,
    float* __restrict__ acc) {
  const int row  = blockIdx.x * 4 + (threadIdx.x >> 6);
  const int lane = threadIdx.x & 63;
  const float4 v0 = ((const float4*)src)[row * 128 + lane * 2];
  const float4 v1 = ((const float4*)src)[row * 128 + lane * 2 + 1];
  float ss = v0.x * v0.x + v0.y * v0.y + v0.z * v0.z + v0.w * v0.w
           + v1.x * v1.x + v1.y * v1.y + v1.z * v1.z + v1.w * v1.w;
  #pragma unroll
  for (int off = 32; off > 0; off >>= 1) ss += __shfl_down(ss, off);
  const float rn = 1.0f / sqrtf(__shfl(ss, 0));   // norms ~22.6, EPS never fires
  if (row == 0 && lane == 0) { acc[0] = 0.0f; ((unsigned int*)acc)[1] = 0u; }
  int pk0 = __builtin_amdgcn_cvt_pk_fp8_f32(v0.x * rn, v0.y * rn, 0, false);
  pk0     = __builtin_amdgcn_cvt_pk_fp8_f32(v0.z * rn, v0.w * rn, pk0, true);
  int pk1 = __builtin_amdgcn_cvt_pk_fp8_f32(v1.x * rn, v1.y * rn, 0, false);
  pk1     = __builtin_amdgcn_cvt_pk_fp8_f32(v1.z * rn, v1.w * rn, pk1, true);
  // lane's 8 logical bytes = 16B chunk cg = lane>>1, half = lane&1.
  const int cg  = lane >> 1;                        // chunk in row (0..31)
  const int win = cg >> 2;                          // 64B window (0..7)
  const int p   = (cg & 3) ^ ((row >> 1) & 3);      // R13 swizzle
  const int hf  = lane & 1;                         // natural half order
  uint2 o; o.x = (unsigned int)pk0; o.y = (unsigned int)pk1;
  ((uint2*)dst)[row * 64 + win * 8 + p * 2 + hf] = o;  // 64B window = 8 uint2
}

__device__ __forceinline__ int tri_base(int b) {   // # tiles before row b
  return b * NT - (b * (b - 1)) / 2;
}

// Kernel 2: fp8 MX-MFMA GEMM (idn @ idn^T) fused with clamp, diag mask,
// full reduction AND final scaling (finalize fused via completion counter).
// R13 geometry: 256x256 tiles, BK=64, 528 blocks, 512 threads (8 waves,
// 2x4 wave grid, 128x64 per wave = 4x2 accs of 32x32). Rationale: R12's MX
// switch was NEUTRAL -> sim is transfer/LDS-bound, not MFMA-bound. Traffic
// scales as (1/BM+1/BN): 256^2 halves L2->LDS bytes (266 MB -> 133 MB).
// Per-CU floors now balanced: transfer ~7.9us, LDS-read ~7.9us (12
// ds_read_b128/thread/stage), MFMA ~7.5us (MX rate) -- vs 17/10/7.5 before.
// Same counted-vmcnt 2-phase pipeline (vmcnt(4): stage t's 4 copies landed,
// t+1's 4 in flight). ~195 VGPR -> 8 waves/CU (launch_bounds(512,2)),
// LDS 64 KB.
__global__ __launch_bounds__(512, 2) void sim_reduce_kernel(
    const unsigned char* __restrict__ idn, float* __restrict__ acc,
    float* __restrict__ out) {
  // triangular decode (block-uniform scalar math, R1-proven)
  const int idx = blockIdx.x;
  const float Af = 2.0f * NT + 1.0f;
  int bi = (int)((Af - sqrtf(Af * Af - 8.0f * (float)idx)) * 0.5f);
  while (bi > 0 && tri_base(bi) > idx) bi--;
  while (tri_base(bi + 1) <= idx) bi++;
  const int bj = bi + (idx - tri_base(bi));

  __shared__ __align__(16) unsigned char As[2][BM * BK];   // 2 x 16 KB
  __shared__ __align__(16) unsigned char Bs[2][BM * BK];   // 2 x 16 KB

  const int tid  = threadIdx.x;      // 0..511, 8 waves
  const int lane = tid & 63;
  const int w    = tid >> 6;
  const int wrow = (w >> 2) * 128;   // wave's 128x64 output block
  const int wcol = (w & 3) * 64;
  const int r32  = lane & 31;        // row within 32-row MFMA tile
  const int h    = lane >> 5;        // k-half selector (k = h*32 + j)
  const int rx   = (r32 >> 1) & 3;   // chunk swizzle key (R13: BK=64)

  f32x16 acc_f[4][2];
  #pragma unroll
  for (int i = 0; i < 4; i++)
    #pragma unroll
    for (int j = 0; j < 2; j++)
      acc_f[i][j] = (f32x16){0.f, 0.f, 0.f, 0.f, 0.f, 0.f, 0.f, 0.f,
                             0.f, 0.f, 0.f, 0.f, 0.f, 0.f, 0.f, 0.f};

  // Staging: per stage, 1024 A-chunks + 1024 B-chunks of 16B. Copy i
  // (i=0,1), thread t covers A-chunk ca = i*512 + t: row = ca>>2, slot =
  // ca&3. LDS dest = ca*16 -> per instruction lane-linear (base + lane*16,
  // global_load_lds constraint). Global src = row*512 + stage*64 + slot*16:
  // memory already holds the swizzled slot order, so staging is a straight
  // copy of each row's 64B window; 4 lanes cover one window contiguously.
  const unsigned char* gA = idn + (size_t)(bi * BM + (tid >> 2)) * KDIM + (tid & 3) * 16;
  const unsigned char* gB = idn + (size_t)(bj * BM + (tid >> 2)) * KDIM + (tid & 3) * 16;
  const int ldso = tid * 16;         // + i*8192 per copy group

  // prologue: stage 0 <- k-window 0
  #pragma unroll
  for (int i = 0; i < 2; i++) async_copy16(gA + (size_t)i * 65536, &As[0][ldso + i * 8192]);
  #pragma unroll
  for (int i = 0; i < 2; i++) async_copy16(gB + (size_t)i * 65536, &Bs[0][ldso + i * 8192]);

  // frag slots: logical chunks c0=2h, c0+1 at swizzled positions (hoisted)
  const int p0 = ((2 * h)     ^ rx) * 16;
  const int p1 = ((2 * h + 1) ^ rx) * 16;

  #pragma unroll
  for (int t = 0; t < NKI; ++t) {
    const int cs = t & 1;
    if (t + 1 < NKI) {
      const int ns = cs ^ 1;
      const int ko = (t + 1) * BK;
      #pragma unroll
      for (int i = 0; i < 2; i++)
        async_copy16(gA + ko + (size_t)i * 65536, &As[ns][ldso + i * 8192]);
      #pragma unroll
      for (int i = 0; i < 2; i++)
        async_copy16(gB + ko + (size_t)i * 65536, &Bs[ns][ldso + i * 8192]);
      asm volatile("s_waitcnt vmcnt(4)" ::: "memory");  // stage t landed; t+1 in flight
    } else {
      asm volatile("s_waitcnt vmcnt(0)" ::: "memory");
    }
    asm volatile("s_barrier" ::: "memory");   // all waves' stage-t fills visible

    // One K=64 slice per stage: 4 A-frags + 2 B-frags, each 2x ds_read_b128.
    i32x8 af[4], bf[2];
    #pragma unroll
    for (int mi = 0; mi < 4; mi++) {
      const unsigned char* ab = &As[cs][(wrow + mi * 32 + r32) * BK];
      const i32x4 alo = *(const i32x4*)(ab + p0);
      const i32x4 ahi = *(const i32x4*)(ab + p1);
      af[mi] = __builtin_shufflevector(alo, ahi, 0, 1, 2, 3, 4, 5, 6, 7);
    }
    #pragma unroll
    for (int ni = 0; ni < 2; ni++) {
      const unsigned char* bb = &Bs[cs][(wcol + ni * 32 + r32) * BK];
      const i32x4 blo = *(const i32x4*)(bb + p0);
      const i32x4 bhi = *(const i32x4*)(bb + p1);
      bf[ni] = __builtin_shufflevector(blo, bhi, 0, 1, 2, 3, 4, 5, 6, 7);
    }
    #pragma unroll
    for (int mi = 0; mi < 4; mi++)
      #pragma unroll
      for (int ni = 0; ni < 2; ni++)
        acc_f[mi][ni] = __builtin_amdgcn_mfma_scale_f32_32x32x64_f8f6f4(
            af[mi], bf[ni], acc_f[mi][ni],
            0, 0,                       // A fmt = fp8 e4m3, B fmt = fp8 e4m3
            0, 0x7F7F7F7Fu,             // A scale: E8M0 127 -> 1.0
            0, 0x7F7F7F7Fu);            // B scale: E8M0 127 -> 1.0

    asm volatile("s_barrier" ::: "memory");   // compute(t) done before t+1 refill
  }

  // Epilogue: clamp at zero, mask diagonal, reduce.
  // C/D layout for 32x32 shapes (m74/m101; dtype-independent m121-m128):
  // col = lane&31, row = (reg&3) + 8*(reg>>2) + 4*(lane>>5). Verified R12.
  float local = 0.f;
  const bool diag = (bi == bj);
  #pragma unroll
  for (int mi = 0; mi < 4; mi++)
    #pragma unroll
    for (int ni = 0; ni < 2; ni++)
      #pragma unroll
      for (int rg = 0; rg < 16; rg++) {
        const int ri = wrow + mi * 32 + (rg & 3) + 8 * (rg >> 2) + 4 * h;
        const int ci = wcol + ni * 32 + r32;
        float v = fmaxf(acc_f[mi][ni][rg], 0.f);
        if (diag && ri == ci) v = 0.f;
        local += v;
      }

  #pragma unroll
  for (int off = 32; off > 0; off >>= 1) local += __shfl_down(local, off);
  __syncthreads();                   // staging dead; reuse As for reduce
  float* red = (float*)As;
  if (lane == 0) red[w] = local;
  __syncthreads();
  if (tid == 0) {
    float s = red[0] + red[1] + red[2] + red[3]
            + red[4] + red[5] + red[6] + red[7];
    if (!diag) s *= 2.f;             // strictly-upper tiles cover both triangles
    atomicAdd(acc, s);
    // fused finalize: last-arriving block scales and writes both outputs.
    __threadfence();                               // acc-add visible before count
    unsigned int done = atomicAdd((unsigned int*)(acc + 1), 1u);
    if (done == NBLK - 1) {
      float total = atomicAdd(acc, 0.0f);          // device-scope RMW read
      const float m = total * (1.0f / ((float)NROWS * (float)NROWS));
      out[0] = m;
      out[1] = m;
    }
  }
}

extern "C" void kernel_launch(void* const* d_in, const int* in_sizes, int n_in,
                              void* d_out, int out_size, void* d_ws, size_t ws_size,
                              hipStream_t stream) {
  const float* id = (const float*)d_in[0];
  float* out = (float*)d_out;
  unsigned char* idn = (unsigned char*)d_ws;                       // 4 MB fp8
  float* acc = (float*)((char*)d_ws + (size_t)NROWS * KDIM);       // [0]=sum, [1]=counter

  prep_kernel<<<NROWS / 4, 256, 0, stream>>>(id, idn, acc);
  sim_reduce_kernel<<<NBLK, 512, 0, stream>>>(idn, acc, out);
}